// Round 2
// 541.979 us; speedup vs baseline: 1.1033x; 1.1033x over previous
//
#include <hip/hip_runtime.h>
#include <stdint.h>
#include <stddef.h>

// B=16, S=512, D=256, L=8192, DROP_P=0.2
#define B_ 16
#define S_ 512
#define D_ 256
#define L_ 8192

typedef unsigned short u16;
typedef _Float16 f16;
typedef f16 f16x4 __attribute__((ext_vector_type(4)));
typedef f16 f16x8 __attribute__((ext_vector_type(8)));   // MFMA A/B frag (4 VGPRs)
typedef float f32x4 __attribute__((ext_vector_type(4))); // MFMA C/D frag

// ---------------------------------------------------------------------------
// async global -> LDS, 16B/lane. LDS dest = wave-uniform base + lane*16.
// ---------------------------------------------------------------------------
__device__ __forceinline__ void gl16(const void* g, void* l) {
  __builtin_amdgcn_global_load_lds(
      (const __attribute__((address_space(1))) unsigned int*)g,
      (__attribute__((address_space(3))) unsigned int*)l, 16, 0, 0);
}

// ---------------------------------------------------------------------------
// JAX threefry2x32 dropout, key=(0,42), partitionable (bit-exact, r1-verified)
// ---------------------------------------------------------------------------
__device__ __forceinline__ uint32_t rotl32(uint32_t x, int r) {
  return (x << r) | (x >> (32 - r));
}
__device__ __forceinline__ bool drop_keep(uint32_t j) {
  const uint32_t k0 = 0u, k1 = 42u, k2 = 0x1BD11BDAu ^ k0 ^ k1;
  uint32_t v0 = 0u + k0;
  uint32_t v1 = j + k1;
#define TF_R(r) { v0 += v1; v1 = rotl32(v1, (r)); v1 ^= v0; }
  TF_R(13) TF_R(15) TF_R(26) TF_R(6)
  v0 += k1; v1 += k2 + 1u;
  TF_R(17) TF_R(29) TF_R(16) TF_R(24)
  v0 += k2; v1 += k0 + 2u;
  TF_R(13) TF_R(15) TF_R(26) TF_R(6)
  v0 += k0; v1 += k1 + 3u;
  TF_R(17) TF_R(29) TF_R(16) TF_R(24)
  v0 += k1; v1 += k2 + 4u;
  TF_R(13) TF_R(15) TF_R(26) TF_R(6)
  v0 += k2; v1 += k0 + 5u;
#undef TF_R
  uint32_t bits = v0 ^ v1;
  float u = __uint_as_float((bits >> 9) | 0x3f800000u) - 1.0f;
  return u < 0.8f;
}

// ---------------------------------------------------------------------------
// prep: fp32 -> fp16 convert (8 elem/thread)
// ---------------------------------------------------------------------------
__global__ __launch_bounds__(256)
void conv16_kernel(const float* __restrict__ src, f16* __restrict__ dst, int n) {
  int i = (blockIdx.x * 256 + threadIdx.x) * 8;
  if (i >= n) return;
  float4 a = *(const float4*)&src[i];
  float4 b = *(const float4*)&src[i + 4];
  f16x8 o;
  o[0] = (f16)a.x; o[1] = (f16)a.y; o[2] = (f16)a.z; o[3] = (f16)a.w;
  o[4] = (f16)b.x; o[5] = (f16)b.y; o[6] = (f16)b.z; o[7] = (f16)b.w;
  *(f16x8*)&dst[i] = o;
}

// x [B][S][D] fp32 -> xT [B][D][S] fp16
__global__ __launch_bounds__(256)
void xt16_kernel(const float* __restrict__ x, f16* __restrict__ xT) {
  const int b = blockIdx.z, sb = blockIdx.x * 32, db = blockIdx.y * 32;
  __shared__ float t[32][33];
  const int tid = threadIdx.x;
  const int r = tid >> 3, c4 = (tid & 7) * 4;
  float4 v = *(const float4*)&x[((size_t)b * S_ + sb + r) * D_ + db + c4];
  t[r][c4] = v.x; t[r][c4 + 1] = v.y; t[r][c4 + 2] = v.z; t[r][c4 + 3] = v.w;
  __syncthreads();
  const int dr = tid >> 3, s4 = (tid & 7) * 4;
  f16x4 o;
#pragma unroll
  for (int j = 0; j < 4; ++j) o[j] = (f16)t[s4 + j][dr];
  *(f16x4*)&xT[((size_t)b * D_ + db + dr) * S_ + sb + s4] = o;
}

// ---------------------------------------------------------------------------
// GEMM1 (fp16 MFMA, NT): scores[b, st.., lt..] = x[s,:] . E[l,:]  (fp32 out)
// 128x128 tile, BK=32. Epilogue: per-row tile max + expsum -> partials.
// ---------------------------------------------------------------------------
__global__ __launch_bounds__(256)
void gemm1_f16(const f16* __restrict__ xh, const f16* __restrict__ eh,
               float* __restrict__ scores, float2* __restrict__ partials,
               int s0, int sc) {
  __shared__ __align__(16) f16 As[128 * 32];
  __shared__ __align__(16) f16 Bs[128 * 32];
  __shared__ float pmaxA[128][2];
  __shared__ float psumA[128][2];

  const int tid = threadIdx.x;
  const int lane = tid & 63, wave = tid >> 6;
  const int b = blockIdx.z, lt = blockIdx.x * 128, st = blockIdx.y * 128;

  const int ra = wave * 32 + (lane >> 2);
  const int kc = (lane & 3) * 8;
  const size_t offA0 = ((size_t)b * S_ + s0 + st + ra) * D_ + kc;
  const size_t offA1 = offA0 + 16 * D_;
  const size_t offB0 = ((size_t)b * L_ + lt + ra) * D_ + kc;
  const size_t offB1 = offB0 + 16 * D_;
  const int lo0 = wave * 2048 + lane * 16;  // bytes

  const int lm = lane & 15, kq = lane >> 4;
  const int wm = (wave & 1) * 64, wn = (wave >> 1) * 64;

  f32x4 acc[4][4] = {};

  for (int k0 = 0; k0 < D_; k0 += 32) {
    __syncthreads();
    gl16(xh + offA0 + k0, (char*)As + lo0);
    gl16(xh + offA1 + k0, (char*)As + lo0 + 1024);
    gl16(eh + offB0 + k0, (char*)Bs + lo0);
    gl16(eh + offB1 + k0, (char*)Bs + lo0 + 1024);
    __syncthreads();

    f16x8 fa[4], fb[4];
#pragma unroll
    for (int mi = 0; mi < 4; ++mi)
      fa[mi] = *(const f16x8*)&As[(wm + mi * 16 + lm) * 32 + kq * 8];
#pragma unroll
    for (int ni = 0; ni < 4; ++ni)
      fb[ni] = *(const f16x8*)&Bs[(wn + ni * 16 + lm) * 32 + kq * 8];
#pragma unroll
    for (int mi = 0; mi < 4; ++mi)
#pragma unroll
      for (int ni = 0; ni < 4; ++ni)
        acc[mi][ni] = __builtin_amdgcn_mfma_f32_16x16x32_f16(
            fa[mi], fb[ni], acc[mi][ni], 0, 0, 0);
  }

  // ---- scores write. C/D: col = lane&15, row = (lane>>4)*4 + reg ----
#pragma unroll
  for (int mi = 0; mi < 4; ++mi)
#pragma unroll
    for (int ni = 0; ni < 4; ++ni) {
      const int m0 = wm + mi * 16 + kq * 4;
      const int n = wn + ni * 16 + lm;
      float* sp = scores + ((size_t)b * sc + st + m0) * L_ + lt + n;
#pragma unroll
      for (int r = 0; r < 4; ++r) sp[(size_t)r * L_] = acc[mi][ni][r];
    }

  // ---- per-row (token) partial max over this 128-col tile ----
  float cmax[4][4];
#pragma unroll
  for (int mi = 0; mi < 4; ++mi)
#pragma unroll
    for (int r = 0; r < 4; ++r) {
      float v = acc[mi][0][r];
      v = fmaxf(v, acc[mi][1][r]);
      v = fmaxf(v, acc[mi][2][r]);
      cmax[mi][r] = fmaxf(v, acc[mi][3][r]);
    }
#pragma unroll
  for (int off = 1; off < 16; off <<= 1)
#pragma unroll
    for (int mi = 0; mi < 4; ++mi)
#pragma unroll
      for (int r = 0; r < 4; ++r)
        cmax[mi][r] = fmaxf(cmax[mi][r], __shfl_xor(cmax[mi][r], off, 64));
  if (lm == 0) {
#pragma unroll
    for (int mi = 0; mi < 4; ++mi)
#pragma unroll
      for (int r = 0; r < 4; ++r)
        pmaxA[wm + mi * 16 + kq * 4 + r][wave >> 1] = cmax[mi][r];
  }
  __syncthreads();
  float rowm[4][4];
#pragma unroll
  for (int mi = 0; mi < 4; ++mi)
#pragma unroll
    for (int r = 0; r < 4; ++r) {
      int row = wm + mi * 16 + kq * 4 + r;
      rowm[mi][r] = fmaxf(pmaxA[row][0], pmaxA[row][1]);
    }
  float psum[4][4] = {};
#pragma unroll
  for (int mi = 0; mi < 4; ++mi)
#pragma unroll
    for (int ni = 0; ni < 4; ++ni)
#pragma unroll
      for (int r = 0; r < 4; ++r)
        psum[mi][r] += __expf(acc[mi][ni][r] - rowm[mi][r]);
#pragma unroll
  for (int off = 1; off < 16; off <<= 1)
#pragma unroll
    for (int mi = 0; mi < 4; ++mi)
#pragma unroll
      for (int r = 0; r < 4; ++r)
        psum[mi][r] += __shfl_xor(psum[mi][r], off, 64);
  if (lm == 0) {
#pragma unroll
    for (int mi = 0; mi < 4; ++mi)
#pragma unroll
      for (int r = 0; r < 4; ++r)
        psumA[wm + mi * 16 + kq * 4 + r][wave >> 1] = psum[mi][r];
  }
  __syncthreads();
  if (tid < 128) {
    float m = fmaxf(pmaxA[tid][0], pmaxA[tid][1]);
    float Z = psumA[tid][0] + psumA[tid][1];
    partials[((size_t)b * 64 + blockIdx.x) * sc + st + tid] = make_float2(m, Z);
  }
}

// ---------------------------------------------------------------------------
// combine partial (m,Z) over 64 l-tiles -> stats (m, factor)
// ---------------------------------------------------------------------------
__global__ __launch_bounds__(256)
void combine_kernel(const float2* __restrict__ partials,
                    const int* __restrict__ mask, float2* __restrict__ stats,
                    int s0, int sc) {
  const int idx = blockIdx.x * 256 + threadIdx.x;  // b*sc + si
  const int b = idx / sc, si = idx - b * sc;
  float m = -3.402823466e38f, Z = 0.f;
  for (int t = 0; t < 64; ++t) {
    float2 p = partials[((size_t)b * 64 + t) * sc + si];
    if (p.x > m) {
      Z = Z * __expf(m - p.x) + p.y;
      m = p.x;
    } else {
      Z += p.y * __expf(p.x - m);
    }
  }
  float f = (mask[b * S_ + s0 + si] != 0) ? (1.25f / Z) : 0.0f;
  stats[idx] = make_float2(m, f);
}

// ---------------------------------------------------------------------------
// GEMM2 fused (fp16 MFMA, full-D tile, K = S = 512):
//   out[b, lt+l, d] = sum_s P(s, lt+l) * x[s, d]
// where P(s,l) = dropout(exp(scores[s][l] - m_s) * f_s) computed ON THE FLY
// from the fp32 scores tile staged in LDS — replaces the tdrop kernel and
// the probsT tensor entirely. Math path is bit-identical to tdrop+gemm2:
// same fp32 exp/normalize, same drop_keep(gidx), same RTN f16 cast, same
// MFMA fragments.
//
// 512 threads = 8 waves. Wave w owns l-rows [w*16, w*16+16), all 256 d cols.
// Each A element (l, s) is computed by exactly one lane, once.
// ---------------------------------------------------------------------------
__global__ __launch_bounds__(512)
void gemm2_fused(const float* __restrict__ scores, const f16* __restrict__ xT,
                 const float2* __restrict__ stats, float* __restrict__ out) {
  __shared__ __align__(16) float Ss[32 * 128];   // 16 KB scores tile [s][l]
  __shared__ __align__(16) f16 Bs[256 * 32];     // 16 KB xT tile [d][s]
  __shared__ float2 stat_s[S_];                  // 4 KB, full-S stats

  const int tid = threadIdx.x;
  const int lane = tid & 63, wave = tid >> 6;
  const int b = blockIdx.z, lt = blockIdx.x * 128;

  // preload stats for this batch row (512 threads -> 512 entries);
  // first __syncthreads() in the loop covers the write->read hazard.
  stat_s[tid] = stats[b * S_ + tid];

  // staging roles: waves 0-3 stage scores (16 chunks of 2 s-rows = 1 KB),
  //                waves 4-7 stage Bs    (16 chunks of 16 d-rows = 1 KB)
  const int sw = wave & 3;
  const bool isB = wave >= 4;
  const size_t sc_base = (size_t)b * S_ * L_ + lt;       // + s*L + l
  const size_t xb_base = (size_t)b * D_ * S_;            // + d*S + k

  const int lm = lane & 15, kq = lane >> 4;
  const int l_loc = wave * 16 + lm;                      // 0..127
  const uint32_t gbase =
      (uint32_t)(b * S_) * (uint32_t)L_ + (uint32_t)(lt + l_loc);

  f32x4 acc[16] = {};

  for (int k0 = 0; k0 < S_; k0 += 32) {
    __syncthreads();
    if (!isB) {
      // scores chunk c covers s-rows {2c, 2c+1}: lane -> s = 2c + (lane>>5),
      // l = (lane&31)*4 floats; LDS linear Ss[s][l].
#pragma unroll
      for (int i = 0; i < 4; ++i) {
        const int c = sw * 4 + i;
        gl16(scores + sc_base + (size_t)(k0 + 2 * c + (lane >> 5)) * L_ +
                 (lane & 31) * 4,
             (char*)Ss + c * 1024);
      }
    } else {
      // Bs chunk c covers d-rows [16c, 16c+16): lane -> d = 16c + (lane>>2),
      // s-off = (lane&3)*8; LDS linear Bs[d][s].
#pragma unroll
      for (int i = 0; i < 4; ++i) {
        const int c = sw * 4 + i;
        gl16(xT + xb_base + (size_t)(c * 16 + (lane >> 2)) * S_ + k0 +
                 (lane & 3) * 8,
             (char*)Bs + c * 1024);
      }
    }
    __syncthreads();

    // ---- build A fragment in-register: P(l_loc, s = kq*8 + j), j=0..7 ----
    float pv[8];
#pragma unroll
    for (int j = 0; j < 8; ++j) {
      const int s_loc = kq * 8 + j;
      const float sc = Ss[s_loc * 128 + l_loc];
      const float2 mf = stat_s[k0 + s_loc];  // broadcast across lm lanes
      pv[j] = __expf(sc - mf.x) * mf.y;
    }
    f16x8 fa;
#pragma unroll
    for (int j = 0; j < 8; ++j) {
      const uint32_t gidx = gbase + (uint32_t)(k0 + kq * 8 + j) * (uint32_t)L_;
      fa[j] = drop_keep(gidx) ? (f16)pv[j] : (f16)0.f;
    }

#pragma unroll
    for (int ni = 0; ni < 16; ++ni) {
      const f16x8 fb = *(const f16x8*)&Bs[(ni * 16 + lm) * 32 + kq * 8];
      acc[ni] = __builtin_amdgcn_mfma_f32_16x16x32_f16(fa, fb, acc[ni], 0, 0, 0);
    }
  }

  // ---- epilogue. C/D: col = lane&15 (d), row = kq*4 + reg (l within 16) ----
#pragma unroll
  for (int ni = 0; ni < 16; ++ni) {
    const int n = ni * 16 + lm;
    float* op = out + ((size_t)b * L_ + lt + wave * 16 + kq * 4) * D_ + n;
#pragma unroll
    for (int r = 0; r < 4; ++r) op[(size_t)r * D_] = acc[ni][r];
  }
}

// ---------------------------------------------------------------------------
extern "C" void kernel_launch(void* const* d_in, const int* in_sizes, int n_in,
                              void* d_out, int out_size, void* d_ws, size_t ws_size,
                              hipStream_t stream) {
  const float* x = (const float*)d_in[0];
  const int* mask = (const int*)d_in[1];
  const float* E = (const float*)d_in[2];
  float* out = (float*)d_out;

  char* ws = (char*)d_ws;
  const size_t nE = (size_t)B_ * L_ * D_;  // 33.5M
  const size_t nX = (size_t)B_ * S_ * D_;  // 2.1M
  size_t o = 0;
  f16* Eh = (f16*)(ws + o); o += nE * 2;                           // 67 MB
  f16* Xh = (f16*)(ws + o); o += nX * 2;                           // 4 MB
  f16* XT = (f16*)(ws + o); o += nX * 2;                           // 4 MB
  float2* stats = (float2*)(ws + o); o += (size_t)B_ * S_ * 8;     // 64 KB
  float2* partials = (float2*)(ws + o); o += (size_t)B_ * 64 * S_ * 8;  // 4 MB
  float* scores = (float*)(ws + o);  // [B][S][L] fp32, 268 MB
  // total ~343 MB; baseline ran the sc=512 path => ws_size >= ~478 MB. Safe.

  conv16_kernel<<<dim3((unsigned)(nE / 8 / 256)), 256, 0, stream>>>(E, Eh, (int)nE);
  conv16_kernel<<<dim3((unsigned)(nX / 8 / 256)), 256, 0, stream>>>(x, Xh, (int)nX);
  xt16_kernel<<<dim3(S_ / 32, D_ / 32, B_), 256, 0, stream>>>(x, XT);

  gemm1_f16<<<dim3(L_ / 128, S_ / 128, B_), 256, 0, stream>>>(
      Xh, Eh, scores, partials, 0, S_);
  combine_kernel<<<dim3(B_ * S_ / 256), 256, 0, stream>>>(partials, mask,
                                                          stats, 0, S_);
  gemm2_fused<<<dim3(L_ / 128, 1, B_), 512, 0, stream>>>(scores, XT, stats, out);
}